// Round 3
// baseline (35165.320 us; speedup 1.0000x reference)
//
#include <hip/hip_runtime.h>

#define T_STEPS 256
#define B_SZ 256
#define H_SZ 1792
#define IN_SZ 160
#define K_SZ (H_SZ + IN_SZ) /* 1952 */
#define BH (B_SZ * H_SZ)    /* 458752 */

__device__ __forceinline__ unsigned rotl32(unsigned x, int r) {
  return (x << r) | (x >> (32 - r));
}

// JAX/Random123 threefry2x32, 20 rounds.
__device__ __forceinline__ void threefry2x32(unsigned k0, unsigned k1,
                                             unsigned x0, unsigned x1,
                                             unsigned& o0, unsigned& o1) {
  unsigned ks2 = k0 ^ k1 ^ 0x1BD11BDAu;
  x0 += k0; x1 += k1;
#define TF_R(r) { x0 += x1; x1 = rotl32(x1, (r)); x1 ^= x0; }
  TF_R(13) TF_R(15) TF_R(26) TF_R(6)
  x0 += k1; x1 += ks2 + 1u;
  TF_R(17) TF_R(29) TF_R(16) TF_R(24)
  x0 += ks2; x1 += k0 + 2u;
  TF_R(13) TF_R(15) TF_R(26) TF_R(6)
  x0 += k0; x1 += k1 + 3u;
  TF_R(17) TF_R(29) TF_R(16) TF_R(24)
  x0 += k1; x1 += ks2 + 4u;
  TF_R(13) TF_R(15) TF_R(26) TF_R(6)
  x0 += ks2; x1 += k0 + 5u;
#undef TF_R
  o0 = x0; o1 = x1;
}

// XLA ErfInv f32 (Giles polynomial) — matches lax.erf_inv lowering.
__device__ __forceinline__ float erfinv_f32(float x) {
  float w = -log1pf(-x * x);
  float p;
  if (w < 5.0f) {
    w -= 2.5f;
    p = 2.81022636e-08f;
    p = fmaf(p, w, 3.43273939e-07f);
    p = fmaf(p, w, -3.5233877e-06f);
    p = fmaf(p, w, -4.39150654e-06f);
    p = fmaf(p, w, 0.00021858087f);
    p = fmaf(p, w, -0.00125372503f);
    p = fmaf(p, w, -0.00417768164f);
    p = fmaf(p, w, 0.246640727f);
    p = fmaf(p, w, 1.50140941f);
  } else {
    w = sqrtf(w) - 3.0f;
    p = -0.000200214257f;
    p = fmaf(p, w, 0.000100950558f);
    p = fmaf(p, w, 0.00134934322f);
    p = fmaf(p, w, -0.00367342844f);
    p = fmaf(p, w, 0.00573950773f);
    p = fmaf(p, w, -0.0076224613f);
    p = fmaf(p, w, 0.00943887047f);
    p = fmaf(p, w, 1.00167406f);
    p = fmaf(p, w, 2.83297682f);
  }
  return p * x;
}

// JAX partitionable threefry random_bits (bit_width=32):
//   counts = u64 iota -> (hi, lo) u32 words; N < 2^32 so hi = 0, lo = e.
//   bits1, bits2 = threefry2x32(key, (0, e));  bits = bits1 ^ bits2  (XOR fold).
__device__ __forceinline__ float jax_normal(unsigned k0, unsigned k1, unsigned e) {
  unsigned o0, o1;
  threefry2x32(k0, k1, 0u, e, o0, o1);
  const unsigned bits = o0 ^ o1; // <- the fix: XOR fold of BOTH output words
  float u = __uint_as_float((bits >> 9) | 0x3F800000u) - 1.0f; // [0,1)
  float z = u * 2.0f + (-0.99999994f); // scale (hi-lo)==2.0f, + minval
  z = fmaxf(-0.99999994f, z);
  return 1.4142135623730951f * erfinv_f32(z);
}

// split(key(42), 256) foldlike (partitionable): key_t = both output words of
// threefry((0,42), (0,t)).
__global__ void init_keys_kernel(unsigned* __restrict__ keybuf) {
  const unsigned t = threadIdx.x; // 256 threads
  unsigned o0, o1;
  threefry2x32(0u, 42u, 0u, t, o0, o1);
  keybuf[2 * t]     = o0;
  keybuf[2 * t + 1] = o1;
}

// Build masked, transposed weight matrix WT[k][h], k in [0,1952):
//   k <  1792 : W_rec[h][k] * mask_rec(h,k)
//   k >= 1792 : W_in[h][k-1792] * mask_in(h,i)
__global__ void build_wt_kernel(const float* __restrict__ W_in,
                                const float* __restrict__ W_rec,
                                float* __restrict__ WT) {
  const int idx = blockIdx.x * 256 + threadIdx.x;
  const int k = idx / H_SZ;
  const int h = idx - k * H_SZ;
  float v;
  if (k < H_SZ) {
    float m;
    if (h < 512)        m = (k < 1536) ? 1.0f : 0.0f;
    else if (h < 1536)  m = 1.0f;
    else                m = (k >= 512) ? 1.0f : 0.0f;
    v = W_rec[(size_t)h * H_SZ + k] * m;
  } else {
    const int i = k - H_SZ;
    float m;
    if (h < 512)        m = (i < 128) ? 1.0f : 0.0f;
    else if (h < 1536)  m = (i >= 128) ? 1.0f : 0.0f;
    else                m = (i >= 64 && i < 128) ? 1.0f : 0.0f;
    v = W_in[(size_t)h * IN_SZ + i] * m;
  }
  WT[idx] = v;
}

__global__ void zero_kernel(float* __restrict__ p, int n) {
  const int i = blockIdx.x * 256 + threadIdx.x;
  if (i < n) p[i] = 0.0f;
}

// One RNN step: total = [prev_out | x_t] @ WT + b_in + b_rec;
// state = state*(1-a) + total*a + sigma*noise; out = relu(state).
// Block: 256 threads, output tile 32(b) x 64(h). Grid 224, XCD-chunk swizzled.
__global__ __launch_bounds__(256) void eirnn_step(
    const float* __restrict__ prev_out, // [B][H]
    const float* __restrict__ x_t,      // [B][IN]
    const float* __restrict__ WT,       // [K][H]
    float* __restrict__ state,          // [B][H]
    const float* __restrict__ b_in,
    const float* __restrict__ b_rec,
    const unsigned* __restrict__ keybuf,
    float* __restrict__ out_t,          // d_out + t*B*H
    int t) {
  __shared__ float ldsA[32][36]; // [k][b], pad 36 -> 16B-aligned float4 reads

  const int tid = threadIdx.x;
  // XCD-chunked swizzle: hw blocks with same (id%8) share an XCD/L2;
  // give each XCD a contiguous range of h-panels.
  const int logical = (blockIdx.x & 7) * 28 + (blockIdx.x >> 3);
  const int tileh = (logical >> 3) * 64; // 28 h-tiles
  const int tileb = (logical & 7) * 32;  // 8 b-tiles
  const int tx = tid & 63; // h lane (one wave = one h-row set, broadcast A)
  const int ty = tid >> 6; // 0..3
  const int h = tileh + tx;

  float acc[8];
#pragma unroll
  for (int j = 0; j < 8; ++j) acc[j] = 0.0f;

  const int k_l = tid & 31;
  const int brow0 = tid >> 5; // 0..7

  for (int tk = 0; tk < K_SZ; tk += 32) {
    const int kg = tk + k_l; // uniform side of 1792 per tile (1792%32==0)
#pragma unroll
    for (int j = 0; j < 4; ++j) {
      const int b_l = brow0 + 8 * j;
      const int b = tileb + b_l;
      float v;
      if (kg < H_SZ) v = prev_out[(size_t)b * H_SZ + kg];
      else           v = x_t[(size_t)b * IN_SZ + (kg - H_SZ)];
      ldsA[k_l][b_l] = v;
    }
    __syncthreads();
    const float* wcol = &WT[(size_t)tk * H_SZ + h];
#pragma unroll
    for (int kk = 0; kk < 32; ++kk) {
      const float w = wcol[(size_t)kk * H_SZ];
      const float4 a0 = *reinterpret_cast<const float4*>(&ldsA[kk][ty * 8]);
      const float4 a1 = *reinterpret_cast<const float4*>(&ldsA[kk][ty * 8 + 4]);
      acc[0] = fmaf(a0.x, w, acc[0]);
      acc[1] = fmaf(a0.y, w, acc[1]);
      acc[2] = fmaf(a0.z, w, acc[2]);
      acc[3] = fmaf(a0.w, w, acc[3]);
      acc[4] = fmaf(a1.x, w, acc[4]);
      acc[5] = fmaf(a1.y, w, acc[5]);
      acc[6] = fmaf(a1.z, w, acc[6]);
      acc[7] = fmaf(a1.w, w, acc[7]);
    }
    __syncthreads();
  }

  const unsigned k0 = keybuf[2 * t];
  const unsigned k1 = keybuf[2 * t + 1];
  const float bias = b_in[h] + b_rec[h];
  // sigma vec (faithful to source bug): 0.1 except h in [1024,1536) -> 0
  const float sig = (h < 1024 || h >= 1536) ? 0.1f : 0.0f;
  const int b0 = tileb + ty * 8;
#pragma unroll
  for (int j = 0; j < 8; ++j) {
    const int b = b0 + j;
    const int e = b * H_SZ + h;
    const float n = jax_normal(k0, k1, (unsigned)e);
    const float total = acc[j] + bias;
    float s = state[e];
    s = s * 0.6666666865348816f + total * 0.3333333432674408f; // f32(1-a), f32(a)
    s += sig * n;
    state[e] = s;
    out_t[e] = fmaxf(s, 0.0f);
  }
}

// Append final (state, out) after the T outputs.
__global__ void finalize_kernel(const float* __restrict__ state,
                                const float* __restrict__ last_out,
                                float* __restrict__ dst) {
  const int i = blockIdx.x * 256 + threadIdx.x;
  dst[i] = state[i];
  dst[BH + i] = last_out[i];
}

extern "C" void kernel_launch(void* const* d_in, const int* in_sizes, int n_in,
                              void* d_out, int out_size, void* d_ws, size_t ws_size,
                              hipStream_t stream) {
  const float* inputs = (const float*)d_in[0]; // [T,B,IN]
  const float* W_in   = (const float*)d_in[1]; // [H,IN]
  const float* b_in   = (const float*)d_in[2]; // [H]
  const float* W_rec  = (const float*)d_in[3]; // [H,H]
  const float* b_rec  = (const float*)d_in[4]; // [H]
  float* out = (float*)d_out;

  // Workspace layout (floats): WT[K*H] | state[BH] | zeros[BH] | keys[512 u32]
  float* WT    = (float*)d_ws;
  float* state = WT + (size_t)K_SZ * H_SZ;
  float* zeros = state + BH;
  unsigned* keybuf = (unsigned*)(zeros + BH);

  init_keys_kernel<<<1, 256, 0, stream>>>(keybuf);
  build_wt_kernel<<<(K_SZ * H_SZ) / 256, 256, 0, stream>>>(W_in, W_rec, WT);
  zero_kernel<<<(2 * BH + 255) / 256, 256, 0, stream>>>(state, 2 * BH);

  for (int t = 0; t < T_STEPS; ++t) {
    const float* prev = (t == 0) ? zeros : (out + (size_t)(t - 1) * BH);
    eirnn_step<<<224, 256, 0, stream>>>(
        prev, inputs + (size_t)t * B_SZ * IN_SZ, WT, state, b_in, b_rec,
        keybuf, out + (size_t)t * BH, t);
  }

  finalize_kernel<<<BH / 256, 256, 0, stream>>>(
      state, out + (size_t)(T_STEPS - 1) * BH, out + (size_t)T_STEPS * BH);
}

// Round 4
// 13112.688 us; speedup vs baseline: 2.6818x; 2.6818x over previous
//
#include <hip/hip_runtime.h>

#define T_STEPS 256
#define B_SZ 256
#define H_SZ 1792
#define IN_SZ 160
#define K_SZ 1952
#define BH (B_SZ * H_SZ) /* 458752 */
#define NSTEP_REC 56     /* recurrent k-steps of 32 */
#define NSTEP_X 5        /* input k-steps of 32 */
#define NFRAG_H 112
#define APK_HALF_U16 (16 * 56 * 3 * 512) /* u16 elems per A_pk buffer */

typedef __attribute__((ext_vector_type(8))) short bf16x8;
typedef __attribute__((ext_vector_type(4))) float f32x4;

__device__ __forceinline__ unsigned rotl32(unsigned x, int r) {
  return (x << r) | (x >> (32 - r));
}

// JAX/Random123 threefry2x32, 20 rounds.
__device__ __forceinline__ void threefry2x32(unsigned k0, unsigned k1,
                                             unsigned x0, unsigned x1,
                                             unsigned& o0, unsigned& o1) {
  unsigned ks2 = k0 ^ k1 ^ 0x1BD11BDAu;
  x0 += k0; x1 += k1;
#define TF_R(r) { x0 += x1; x1 = rotl32(x1, (r)); x1 ^= x0; }
  TF_R(13) TF_R(15) TF_R(26) TF_R(6)
  x0 += k1; x1 += ks2 + 1u;
  TF_R(17) TF_R(29) TF_R(16) TF_R(24)
  x0 += ks2; x1 += k0 + 2u;
  TF_R(13) TF_R(15) TF_R(26) TF_R(6)
  x0 += k0; x1 += k1 + 3u;
  TF_R(17) TF_R(29) TF_R(16) TF_R(24)
  x0 += k1; x1 += ks2 + 4u;
  TF_R(13) TF_R(15) TF_R(26) TF_R(6)
  x0 += ks2; x1 += k0 + 5u;
#undef TF_R
  o0 = x0; o1 = x1;
}

// XLA ErfInv f32 (Giles polynomial).
__device__ __forceinline__ float erfinv_f32(float x) {
  float w = -log1pf(-x * x);
  float p;
  if (w < 5.0f) {
    w -= 2.5f;
    p = 2.81022636e-08f;
    p = fmaf(p, w, 3.43273939e-07f);
    p = fmaf(p, w, -3.5233877e-06f);
    p = fmaf(p, w, -4.39150654e-06f);
    p = fmaf(p, w, 0.00021858087f);
    p = fmaf(p, w, -0.00125372503f);
    p = fmaf(p, w, -0.00417768164f);
    p = fmaf(p, w, 0.246640727f);
    p = fmaf(p, w, 1.50140941f);
  } else {
    w = sqrtf(w) - 3.0f;
    p = -0.000200214257f;
    p = fmaf(p, w, 0.000100950558f);
    p = fmaf(p, w, 0.00134934322f);
    p = fmaf(p, w, -0.00367342844f);
    p = fmaf(p, w, 0.00573950773f);
    p = fmaf(p, w, -0.0076224613f);
    p = fmaf(p, w, 0.00943887047f);
    p = fmaf(p, w, 1.00167406f);
    p = fmaf(p, w, 2.83297682f);
  }
  return p * x;
}

// JAX partitionable threefry random bits: bits = o0 ^ o1 of threefry(key,(0,e)).
__device__ __forceinline__ float jax_normal(unsigned k0, unsigned k1, unsigned e) {
  unsigned o0, o1;
  threefry2x32(k0, k1, 0u, e, o0, o1);
  const unsigned bits = o0 ^ o1;
  float u = __uint_as_float((bits >> 9) | 0x3F800000u) - 1.0f;
  float z = u * 2.0f + (-0.99999994f);
  z = fmaxf(-0.99999994f, z);
  return 1.4142135623730951f * erfinv_f32(z);
}

__global__ void init_keys_kernel(unsigned* __restrict__ keybuf) {
  const unsigned t = threadIdx.x;
  unsigned o0, o1;
  threefry2x32(0u, 42u, 0u, t, o0, o1);
  keybuf[2 * t] = o0;
  keybuf[2 * t + 1] = o1;
}

// ---- bf16x3 split helpers -------------------------------------------------
__device__ __forceinline__ unsigned short bf16_rne(float f) {
  unsigned u = __float_as_uint(f);
  unsigned r = u + 0x7FFFu + ((u >> 16) & 1u);
  return (unsigned short)(r >> 16);
}
__device__ __forceinline__ float bf16_f32(unsigned short h) {
  return __uint_as_float(((unsigned)h) << 16);
}
__device__ __forceinline__ void split3(float w, unsigned short& h,
                                       unsigned short& m, unsigned short& l) {
  h = bf16_rne(w);
  float r = w - bf16_f32(h);
  m = bf16_rne(r);
  r -= bf16_f32(m);
  l = bf16_rne(r);
}

// ---- pack W (masked, transposed, bf16x3, MFMA-fragment order) -------------
// B_pk[s][f][p] : 1KB frag; element (lane,j): B[k=32s+8*(lane>>4)+j][h=16f+(lane&15)]
__global__ void pack_B_kernel(const float* __restrict__ W_in,
                              const float* __restrict__ W_rec,
                              unsigned short* __restrict__ Bpk) {
  const int id = blockIdx.x * 256 + threadIdx.x; // 437248 threads
  const int h = id / 244;
  const int ko = id - h * 244; // k-octet
  const int k0 = ko * 8;
  float w[8];
  if (k0 < H_SZ) {
    const float4* src = reinterpret_cast<const float4*>(&W_rec[(size_t)h * H_SZ + k0]);
    float4 v0 = src[0], v1 = src[1];
    float m;
    if (h < 512)       m = (k0 < 1536) ? 1.0f : 0.0f;
    else if (h < 1536) m = 1.0f;
    else               m = (k0 >= 512) ? 1.0f : 0.0f;
    w[0]=v0.x*m; w[1]=v0.y*m; w[2]=v0.z*m; w[3]=v0.w*m;
    w[4]=v1.x*m; w[5]=v1.y*m; w[6]=v1.z*m; w[7]=v1.w*m;
  } else {
    const int i0 = k0 - H_SZ;
    const float4* src = reinterpret_cast<const float4*>(&W_in[(size_t)h * IN_SZ + i0]);
    float4 v0 = src[0], v1 = src[1];
    float m;
    if (h < 512)       m = (i0 < 128) ? 1.0f : 0.0f;
    else if (h < 1536) m = (i0 >= 128) ? 1.0f : 0.0f;
    else               m = (i0 >= 64 && i0 < 128) ? 1.0f : 0.0f;
    w[0]=v0.x*m; w[1]=v0.y*m; w[2]=v0.z*m; w[3]=v0.w*m;
    w[4]=v1.x*m; w[5]=v1.y*m; w[6]=v1.z*m; w[7]=v1.w*m;
  }
  bf16x8 vh, vm, vl;
#pragma unroll
  for (int j = 0; j < 8; ++j) {
    unsigned short a, b, c;
    split3(w[j], a, b, c);
    vh[j] = (short)a; vm[j] = (short)b; vl[j] = (short)c;
  }
  const int s = ko >> 2;
  const int f = h >> 4;
  const int lane = (h & 15) + 16 * (ko & 3);
  unsigned short* dst = Bpk + ((size_t)(s * NFRAG_H + f) * 3) * 512 + lane * 8;
  *reinterpret_cast<bf16x8*>(dst)        = vh;
  *reinterpret_cast<bf16x8*>(dst + 512)  = vm;
  *reinterpret_cast<bf16x8*>(dst + 1024) = vl;
}

// ---- pack inputs (bf16x3 A-side fragments, per t) -------------------------
// X_pk[t][bf][sx][p] frag; element (lane,j): x[t][b=16bf+(lane&15)][i=32sx+8*(lane>>4)+j]
__global__ void pack_x_kernel(const float* __restrict__ inputs,
                              unsigned short* __restrict__ Xpk) {
  const int id = blockIdx.x * 256 + threadIdx.x; // 1310720 threads
  const int io = id % 20;
  const int tb = id / 20;
  const int b = tb & 255;
  const int t = tb >> 8;
  const float4* src = reinterpret_cast<const float4*>(
      &inputs[((size_t)(t * 256 + b)) * IN_SZ + io * 8]);
  float4 v0 = src[0], v1 = src[1];
  float w[8] = {v0.x, v0.y, v0.z, v0.w, v1.x, v1.y, v1.z, v1.w};
  bf16x8 vh, vm, vl;
#pragma unroll
  for (int j = 0; j < 8; ++j) {
    unsigned short a, bb, c;
    split3(w[j], a, bb, c);
    vh[j] = (short)a; vm[j] = (short)bb; vl[j] = (short)c;
  }
  const int sx = io >> 2;
  const int lane = (b & 15) + 16 * (io & 3);
  unsigned short* dst = Xpk +
      ((size_t)((t * 16 + (b >> 4)) * NSTEP_X + sx) * 3) * 512 + lane * 8;
  *reinterpret_cast<bf16x8*>(dst)        = vh;
  *reinterpret_cast<bf16x8*>(dst + 512)  = vm;
  *reinterpret_cast<bf16x8*>(dst + 1024) = vl;
}

__global__ void zero_kernel(float* __restrict__ p, int n) {
  const int i = blockIdx.x * 256 + threadIdx.x;
  if (i < n) p[i] = 0.0f;
}

// ---- one RNN step ---------------------------------------------------------
// grid 224 = 8 b-blocks (32b) x 28 h-blocks (64h); 256 thr: waves 0,1 = GEMM
// (each 32b x 32h via 2x2 16x16x32 frags, bf16x3 6-term), waves 0-3 epilogue.
__global__ __launch_bounds__(256) void eirnn_step(
    const unsigned short* __restrict__ Apk_cur,
    unsigned short* __restrict__ Apk_next,
    const unsigned short* __restrict__ Xpk_t,
    const unsigned short* __restrict__ Bpk,
    float* __restrict__ state,
    const float* __restrict__ b_in, const float* __restrict__ b_rec,
    const unsigned* __restrict__ keybuf,
    float* __restrict__ out_t, int t) {
  __shared__ float ldsC[32][64];

  const int tid = threadIdx.x;
  const int w = tid >> 6;
  const int lane = tid & 63;
  const int logical = (blockIdx.x & 7) * 28 + (blockIdx.x >> 3);
  const int hb = logical >> 3;      // 0..27 (64h)
  const int bb = logical & 7;       // 0..7  (32b)
  const int b0 = bb * 32;

  if (w < 2) {
    const int f0 = (hb * 64 + w * 32) >> 4; // h-frag base (2 frags)
    const int bf0 = b0 >> 4;                // b-frag base (2 frags)
    const int lofs = lane * 8;

    f32x4 acc[2][2] = {};

    // recurrent K (s = 0..55) then input K (s = 56..60)
    for (int s = 0; s < NSTEP_REC + NSTEP_X; ++s) {
      bf16x8 a[2][3], bq[2][3];
#pragma unroll
      for (int pi = 0; pi < 2; ++pi) {
        const unsigned short* ap;
        if (s < NSTEP_REC)
          ap = Apk_cur + ((size_t)(((bf0 + pi) * NSTEP_REC + s) * 3)) * 512;
        else
          ap = Xpk_t + ((size_t)(((bf0 + pi) * NSTEP_X + (s - NSTEP_REC)) * 3)) * 512;
#pragma unroll
        for (int p = 0; p < 3; ++p)
          a[pi][p] = *reinterpret_cast<const bf16x8*>(ap + p * 512 + lofs);
      }
#pragma unroll
      for (int qi = 0; qi < 2; ++qi) {
        const unsigned short* bp =
            Bpk + ((size_t)((s * NFRAG_H + f0 + qi) * 3)) * 512;
#pragma unroll
        for (int p = 0; p < 3; ++p)
          bq[qi][p] = *reinterpret_cast<const bf16x8*>(bp + p * 512 + lofs);
      }
#pragma unroll
      for (int pi = 0; pi < 2; ++pi)
#pragma unroll
        for (int qi = 0; qi < 2; ++qi) {
          f32x4 c = acc[pi][qi];
          c = __builtin_amdgcn_mfma_f32_16x16x32_bf16(a[pi][0], bq[qi][0], c, 0, 0, 0);
          c = __builtin_amdgcn_mfma_f32_16x16x32_bf16(a[pi][0], bq[qi][1], c, 0, 0, 0);
          c = __builtin_amdgcn_mfma_f32_16x16x32_bf16(a[pi][1], bq[qi][0], c, 0, 0, 0);
          c = __builtin_amdgcn_mfma_f32_16x16x32_bf16(a[pi][0], bq[qi][2], c, 0, 0, 0);
          c = __builtin_amdgcn_mfma_f32_16x16x32_bf16(a[pi][2], bq[qi][0], c, 0, 0, 0);
          c = __builtin_amdgcn_mfma_f32_16x16x32_bf16(a[pi][1], bq[qi][1], c, 0, 0, 0);
          acc[pi][qi] = c;
        }
    }
    // scatter acc to LDS: row = b-local, col = h-local (C/D: row=(lane>>4)*4+r, col=lane&15)
#pragma unroll
    for (int pi = 0; pi < 2; ++pi)
#pragma unroll
      for (int qi = 0; qi < 2; ++qi) {
        const int row = pi * 16 + (lane >> 4) * 4;
        const int col = w * 32 + qi * 16 + (lane & 15);
        ldsC[row + 0][col] = acc[pi][qi][0];
        ldsC[row + 1][col] = acc[pi][qi][1];
        ldsC[row + 2][col] = acc[pi][qi][2];
        ldsC[row + 3][col] = acc[pi][qi][3];
      }
  }
  __syncthreads();

  // epilogue: 256 threads, each owns (b-local, h-octet): 8 elements
  const unsigned kk0 = keybuf[2 * t];
  const unsigned kk1 = keybuf[2 * t + 1];
  const int oct = tid & 7;
  const int bl = (tid >> 3) & 31;
  const int b = b0 + bl;
  const int hbase = hb * 64 + oct * 8;
  const size_t e = (size_t)b * H_SZ + hbase;

  float sv[8], av[8];
  {
    const f32x4 s0 = *reinterpret_cast<const f32x4*>(&state[e]);
    const f32x4 s1 = *reinterpret_cast<const f32x4*>(&state[e + 4]);
#pragma unroll
    for (int j = 0; j < 4; ++j) { sv[j] = s0[j]; sv[4 + j] = s1[j]; }
#pragma unroll
    for (int j = 0; j < 8; ++j) av[j] = ldsC[bl][oct * 8 + j];
  }
  const f32x4 bi0 = *reinterpret_cast<const f32x4*>(&b_in[hbase]);
  const f32x4 bi1 = *reinterpret_cast<const f32x4*>(&b_in[hbase + 4]);
  const f32x4 br0 = *reinterpret_cast<const f32x4*>(&b_rec[hbase]);
  const f32x4 br1 = *reinterpret_cast<const f32x4*>(&b_rec[hbase + 4]);

  f32x4 so0, so1, oo0, oo1;
  bf16x8 vh, vm, vl;
#pragma unroll
  for (int j = 0; j < 8; ++j) {
    const int h = hbase + j;
    const float bias = (j < 4 ? bi0[j] : bi1[j - 4]) + (j < 4 ? br0[j] : br1[j - 4]);
    const float sig = (h < 1024 || h >= 1536) ? 0.1f : 0.0f;
    const float n = jax_normal(kk0, kk1, (unsigned)(e + j));
    float s = sv[j] * 0.6666666865348816f + (av[j] + bias) * 0.3333333432674408f;
    s += sig * n;
    const float o = fmaxf(s, 0.0f);
    if (j < 4) { so0[j] = s; oo0[j] = o; } else { so1[j - 4] = s; oo1[j - 4] = o; }
    unsigned short xh, xm, xl;
    split3(o, xh, xm, xl);
    vh[j] = (short)xh; vm[j] = (short)xm; vl[j] = (short)xl;
  }
  *reinterpret_cast<f32x4*>(&state[e]) = so0;
  *reinterpret_cast<f32x4*>(&state[e + 4]) = so1;
  *reinterpret_cast<f32x4*>(&out_t[e]) = oo0;
  *reinterpret_cast<f32x4*>(&out_t[e + 4]) = oo1;

  // pre-split A fragments for next step
  unsigned short* dst = Apk_next +
      ((size_t)(((b >> 4) * NSTEP_REC + (hbase >> 5)) * 3)) * 512 +
      ((b & 15) + 16 * ((hbase >> 3) & 3)) * 8;
  *reinterpret_cast<bf16x8*>(dst)        = vh;
  *reinterpret_cast<bf16x8*>(dst + 512)  = vm;
  *reinterpret_cast<bf16x8*>(dst + 1024) = vl;
}

__global__ void finalize_kernel(const float* __restrict__ state,
                                const float* __restrict__ last_out,
                                float* __restrict__ dst) {
  const int i = blockIdx.x * 256 + threadIdx.x;
  dst[i] = state[i];
  dst[BH + i] = last_out[i];
}

extern "C" void kernel_launch(void* const* d_in, const int* in_sizes, int n_in,
                              void* d_out, int out_size, void* d_ws, size_t ws_size,
                              hipStream_t stream) {
  const float* inputs = (const float*)d_in[0];
  const float* W_in   = (const float*)d_in[1];
  const float* b_in   = (const float*)d_in[2];
  const float* W_rec  = (const float*)d_in[3];
  const float* b_rec  = (const float*)d_in[4];
  float* out = (float*)d_out;

  char* ws = (char*)d_ws;
  unsigned short* Bpk = (unsigned short*)ws;                       // 20,987,904 B
  unsigned short* Xpk = (unsigned short*)(ws + 20987904);          // 62,914,560 B
  unsigned short* Apk = (unsigned short*)(ws + 83902464);          // 5,505,024 B
  float* state = (float*)(ws + 89407488);                          // 1,835,008 B
  unsigned* keybuf = (unsigned*)(ws + 91242496);                   // 2,048 B

  init_keys_kernel<<<1, 256, 0, stream>>>(keybuf);
  pack_B_kernel<<<1708, 256, 0, stream>>>(W_in, W_rec, Bpk);
  pack_x_kernel<<<5120, 256, 0, stream>>>(inputs, Xpk);
  zero_kernel<<<1792, 256, 0, stream>>>(state, BH);
  zero_kernel<<<2688, 256, 0, stream>>>((float*)Apk, APK_HALF_U16 / 2);

  for (int t = 0; t < T_STEPS; ++t) {
    const int par = t & 1;
    eirnn_step<<<224, 256, 0, stream>>>(
        Apk + (size_t)par * APK_HALF_U16,
        Apk + (size_t)(par ^ 1) * APK_HALF_U16,
        Xpk + (size_t)t * (16 * NSTEP_X * 3 * 512),
        Bpk, state, b_in, b_rec, keybuf, out + (size_t)t * BH, t);
  }

  finalize_kernel<<<1792, 256, 0, stream>>>(
      state, out + (size_t)(T_STEPS - 1) * BH, out + (size_t)T_STEPS * BH);
}

// Round 5
// 8601.042 us; speedup vs baseline: 4.0885x; 1.5245x over previous
//
#include <hip/hip_runtime.h>

#define T_STEPS 256
#define B_SZ 256
#define H_SZ 1792
#define IN_SZ 160
#define BH (B_SZ * H_SZ) /* 458752 */
#define NSTEP_REC 56
#define NSTEP_X 5
#define NFRAG_H 112
#define APK_HALF (16 * NSTEP_REC * 2 * 512) /* fp16 elems per A buffer: 917504 */

typedef __attribute__((ext_vector_type(8))) _Float16 f16x8;
typedef __attribute__((ext_vector_type(4))) float f32x4;

__device__ __forceinline__ unsigned rotl32(unsigned x, int r) {
  return (x << r) | (x >> (32 - r));
}

__device__ __forceinline__ void threefry2x32(unsigned k0, unsigned k1,
                                             unsigned x0, unsigned x1,
                                             unsigned& o0, unsigned& o1) {
  unsigned ks2 = k0 ^ k1 ^ 0x1BD11BDAu;
  x0 += k0; x1 += k1;
#define TF_R(r) { x0 += x1; x1 = rotl32(x1, (r)); x1 ^= x0; }
  TF_R(13) TF_R(15) TF_R(26) TF_R(6)
  x0 += k1; x1 += ks2 + 1u;
  TF_R(17) TF_R(29) TF_R(16) TF_R(24)
  x0 += ks2; x1 += k0 + 2u;
  TF_R(13) TF_R(15) TF_R(26) TF_R(6)
  x0 += k0; x1 += k1 + 3u;
  TF_R(17) TF_R(29) TF_R(16) TF_R(24)
  x0 += k1; x1 += ks2 + 4u;
  TF_R(13) TF_R(15) TF_R(26) TF_R(6)
  x0 += ks2; x1 += k0 + 5u;
#undef TF_R
  o0 = x0; o1 = x1;
}

__device__ __forceinline__ float erfinv_f32(float x) {
  float w = -log1pf(-x * x);
  float p;
  if (w < 5.0f) {
    w -= 2.5f;
    p = 2.81022636e-08f;
    p = fmaf(p, w, 3.43273939e-07f);
    p = fmaf(p, w, -3.5233877e-06f);
    p = fmaf(p, w, -4.39150654e-06f);
    p = fmaf(p, w, 0.00021858087f);
    p = fmaf(p, w, -0.00125372503f);
    p = fmaf(p, w, -0.00417768164f);
    p = fmaf(p, w, 0.246640727f);
    p = fmaf(p, w, 1.50140941f);
  } else {
    w = sqrtf(w) - 3.0f;
    p = -0.000200214257f;
    p = fmaf(p, w, 0.000100950558f);
    p = fmaf(p, w, 0.00134934322f);
    p = fmaf(p, w, -0.00367342844f);
    p = fmaf(p, w, 0.00573950773f);
    p = fmaf(p, w, -0.0076224613f);
    p = fmaf(p, w, 0.00943887047f);
    p = fmaf(p, w, 1.00167406f);
    p = fmaf(p, w, 2.83297682f);
  }
  return p * x;
}

// JAX partitionable threefry bits = o0 ^ o1 of threefry(key, (0, e)).
__device__ __forceinline__ float jax_normal(unsigned k0, unsigned k1, unsigned e) {
  unsigned o0, o1;
  threefry2x32(k0, k1, 0u, e, o0, o1);
  const unsigned bits = o0 ^ o1;
  float u = __uint_as_float((bits >> 9) | 0x3F800000u) - 1.0f;
  float z = u * 2.0f + (-0.99999994f);
  z = fmaxf(-0.99999994f, z);
  return 1.4142135623730951f * erfinv_f32(z);
}

__global__ void init_keys_kernel(unsigned* __restrict__ keybuf) {
  const unsigned t = threadIdx.x;
  unsigned o0, o1;
  threefry2x32(0u, 42u, 0u, t, o0, o1);
  keybuf[2 * t] = o0;
  keybuf[2 * t + 1] = o1;
}

// fp16 2-way split: w ~= h + m/2048 (m pre-scaled to stay normal).
__device__ __forceinline__ void split2(float w, _Float16& h, _Float16& m) {
  h = (_Float16)w;
  float r = w - (float)h;
  m = (_Float16)(r * 2048.0f);
}

// B_pk[s][f][p][512] : frag elem(lane,j) = B[k=32s+8*(lane>>4)+j][h=16f+(lane&15)]
__global__ void pack_B_kernel(const float* __restrict__ W_in,
                              const float* __restrict__ W_rec,
                              _Float16* __restrict__ Bpk) {
  const int id = blockIdx.x * 256 + threadIdx.x; // 437248
  const int h = id / 244;
  const int ko = id - h * 244;
  const int k0 = ko * 8;
  float w[8];
  if (k0 < H_SZ) {
    const float4* src = reinterpret_cast<const float4*>(&W_rec[(size_t)h * H_SZ + k0]);
    float4 v0 = src[0], v1 = src[1];
    float m;
    if (h < 512)       m = (k0 < 1536) ? 1.0f : 0.0f;
    else if (h < 1536) m = 1.0f;
    else               m = (k0 >= 512) ? 1.0f : 0.0f;
    w[0]=v0.x*m; w[1]=v0.y*m; w[2]=v0.z*m; w[3]=v0.w*m;
    w[4]=v1.x*m; w[5]=v1.y*m; w[6]=v1.z*m; w[7]=v1.w*m;
  } else {
    const int i0 = k0 - H_SZ;
    const float4* src = reinterpret_cast<const float4*>(&W_in[(size_t)h * IN_SZ + i0]);
    float4 v0 = src[0], v1 = src[1];
    float m;
    if (h < 512)       m = (i0 < 128) ? 1.0f : 0.0f;
    else if (h < 1536) m = (i0 >= 128) ? 1.0f : 0.0f;
    else               m = (i0 >= 64 && i0 < 128) ? 1.0f : 0.0f;
    w[0]=v0.x*m; w[1]=v0.y*m; w[2]=v0.z*m; w[3]=v0.w*m;
    w[4]=v1.x*m; w[5]=v1.y*m; w[6]=v1.z*m; w[7]=v1.w*m;
  }
  f16x8 vh, vm;
#pragma unroll
  for (int j = 0; j < 8; ++j) {
    _Float16 a, b;
    split2(w[j], a, b);
    vh[j] = a; vm[j] = b;
  }
  const int s = ko >> 2;
  const int f = h >> 4;
  const int lane = (h & 15) + 16 * (ko & 3);
  _Float16* dst = Bpk + ((size_t)(s * NFRAG_H + f) * 2) * 512 + lane * 8;
  *reinterpret_cast<f16x8*>(dst)       = vh;
  *reinterpret_cast<f16x8*>(dst + 512) = vm;
}

// X_pk[t][bf][sx][p][512] : elem(lane,j) = x[t][b=16bf+(lane&15)][i=32sx+8*(lane>>4)+j]
__global__ void pack_x_kernel(const float* __restrict__ inputs,
                              _Float16* __restrict__ Xpk) {
  const int id = blockIdx.x * 256 + threadIdx.x; // 1310720
  const int io = id % 20;
  const int tb = id / 20;
  const int b = tb & 255;
  const int t = tb >> 8;
  const float4* src = reinterpret_cast<const float4*>(
      &inputs[((size_t)(t * 256 + b)) * IN_SZ + io * 8]);
  float4 v0 = src[0], v1 = src[1];
  float w[8] = {v0.x, v0.y, v0.z, v0.w, v1.x, v1.y, v1.z, v1.w};
  f16x8 vh, vm;
#pragma unroll
  for (int j = 0; j < 8; ++j) {
    _Float16 a, bb;
    split2(w[j], a, bb);
    vh[j] = a; vm[j] = bb;
  }
  const int sx = io >> 2;
  const int lane = (b & 15) + 16 * (io & 3);
  _Float16* dst = Xpk +
      ((size_t)((t * 16 + (b >> 4)) * NSTEP_X + sx) * 2) * 512 + lane * 8;
  *reinterpret_cast<f16x8*>(dst)       = vh;
  *reinterpret_cast<f16x8*>(dst + 512) = vm;
}

__global__ void zero_kernel(float* __restrict__ p, int n) {
  const int i = blockIdx.x * 256 + threadIdx.x;
  if (i < n) p[i] = 0.0f;
}

// grid 112 = 4 bb (64b) x 28 hb (64h); 4 waves, each 32b x 32h (2x2 frags).
__global__ __launch_bounds__(256) void eirnn_step(
    const _Float16* __restrict__ Apk_cur,
    _Float16* __restrict__ Apk_next,
    const _Float16* __restrict__ Xpk_t,
    const _Float16* __restrict__ Bpk,
    float* __restrict__ state,
    const float* __restrict__ b_in, const float* __restrict__ b_rec,
    const unsigned* __restrict__ keybuf,
    float* __restrict__ out_t, int t) {
  __shared__ float ldsC[64][68]; // stride 68 floats: 16B-aligned rows, low conflict

  const int tid = threadIdx.x;
  const int w = tid >> 6;
  const int lane = tid & 63;
  // XCD-chunked swizzle: XCD x owns logical [14x, 14x+14) -> contiguous hb range.
  const int logical = (blockIdx.x & 7) * 14 + (blockIdx.x >> 3);
  const int hb = logical >> 2;  // 0..27
  const int bb = logical & 3;   // 0..3
  const int b0 = bb * 64;
  const int wb = w >> 1, wh = w & 1;
  const int bf0 = (b0 + wb * 32) >> 4;
  const int f0 = (hb * 64 + wh * 32) >> 4;
  const int lofs = lane * 8;

  f32x4 acc1[2][2] = {};
  f32x4 acc2[2][2] = {};

  const _Float16* aP0 = Apk_cur + ((size_t)(bf0 * NSTEP_REC) * 2) * 512 + lofs;
  const _Float16* aP1 = Apk_cur + ((size_t)((bf0 + 1) * NSTEP_REC) * 2) * 512 + lofs;
  const _Float16* bP = Bpk + ((size_t)(f0 * 2)) * 512 + lofs;

#define GEMM_BODY(A0H, A0M, A1H, A1M)                                          \
  {                                                                            \
    f16x8 b0h = *reinterpret_cast<const f16x8*>(bP);                           \
    f16x8 b0m = *reinterpret_cast<const f16x8*>(bP + 512);                     \
    f16x8 b1h = *reinterpret_cast<const f16x8*>(bP + 1024);                    \
    f16x8 b1m = *reinterpret_cast<const f16x8*>(bP + 1536);                    \
    acc1[0][0] = __builtin_amdgcn_mfma_f32_16x16x32_f16(A0H, b0h, acc1[0][0], 0, 0, 0); \
    acc2[0][0] = __builtin_amdgcn_mfma_f32_16x16x32_f16(A0H, b0m, acc2[0][0], 0, 0, 0); \
    acc2[0][0] = __builtin_amdgcn_mfma_f32_16x16x32_f16(A0M, b0h, acc2[0][0], 0, 0, 0); \
    acc1[0][1] = __builtin_amdgcn_mfma_f32_16x16x32_f16(A0H, b1h, acc1[0][1], 0, 0, 0); \
    acc2[0][1] = __builtin_amdgcn_mfma_f32_16x16x32_f16(A0H, b1m, acc2[0][1], 0, 0, 0); \
    acc2[0][1] = __builtin_amdgcn_mfma_f32_16x16x32_f16(A0M, b1h, acc2[0][1], 0, 0, 0); \
    acc1[1][0] = __builtin_amdgcn_mfma_f32_16x16x32_f16(A1H, b0h, acc1[1][0], 0, 0, 0); \
    acc2[1][0] = __builtin_amdgcn_mfma_f32_16x16x32_f16(A1H, b0m, acc2[1][0], 0, 0, 0); \
    acc2[1][0] = __builtin_amdgcn_mfma_f32_16x16x32_f16(A1M, b0h, acc2[1][0], 0, 0, 0); \
    acc1[1][1] = __builtin_amdgcn_mfma_f32_16x16x32_f16(A1H, b1h, acc1[1][1], 0, 0, 0); \
    acc2[1][1] = __builtin_amdgcn_mfma_f32_16x16x32_f16(A1H, b1m, acc2[1][1], 0, 0, 0); \
    acc2[1][1] = __builtin_amdgcn_mfma_f32_16x16x32_f16(A1M, b1h, acc2[1][1], 0, 0, 0); \
  }

#pragma unroll 4
  for (int s = 0; s < NSTEP_REC; ++s) {
    f16x8 a0h = *reinterpret_cast<const f16x8*>(aP0);
    f16x8 a0m = *reinterpret_cast<const f16x8*>(aP0 + 512);
    f16x8 a1h = *reinterpret_cast<const f16x8*>(aP1);
    f16x8 a1m = *reinterpret_cast<const f16x8*>(aP1 + 512);
    GEMM_BODY(a0h, a0m, a1h, a1m)
    aP0 += 1024; aP1 += 1024;
    bP += (size_t)NFRAG_H * 1024;
  }
  {
    const _Float16* xP0 = Xpk_t + ((size_t)(bf0 * NSTEP_X) * 2) * 512 + lofs;
    const _Float16* xP1 = Xpk_t + ((size_t)((bf0 + 1) * NSTEP_X) * 2) * 512 + lofs;
#pragma unroll
    for (int sx = 0; sx < NSTEP_X; ++sx) {
      f16x8 a0h = *reinterpret_cast<const f16x8*>(xP0);
      f16x8 a0m = *reinterpret_cast<const f16x8*>(xP0 + 512);
      f16x8 a1h = *reinterpret_cast<const f16x8*>(xP1);
      f16x8 a1m = *reinterpret_cast<const f16x8*>(xP1 + 512);
      GEMM_BODY(a0h, a0m, a1h, a1m)
      xP0 += 1024; xP1 += 1024;
      bP += (size_t)NFRAG_H * 1024;
    }
  }
#undef GEMM_BODY

  // scatter C to LDS: row = b-local, col = h-local (verified R4 convention)
#pragma unroll
  for (int pi = 0; pi < 2; ++pi)
#pragma unroll
    for (int qi = 0; qi < 2; ++qi) {
      const int row = wb * 32 + pi * 16 + ((lane >> 4) << 2);
      const int col = wh * 32 + qi * 16 + (lane & 15);
#pragma unroll
      for (int r = 0; r < 4; ++r)
        ldsC[row + r][col] = acc1[pi][qi][r] + acc2[pi][qi][r] * (1.0f / 2048.0f);
    }
  __syncthreads();

  // epilogue: thread -> b-row (bl = tid>>2), h-16-chunk (c = tid&3)
  const unsigned kk0 = keybuf[2 * t];
  const unsigned kk1 = keybuf[2 * t + 1];
  const int bl = tid >> 2;
  const int c = tid & 3;
  const int b = b0 + bl;
  const int hbase = hb * 64 + c * 16;
  const size_t e = (size_t)b * H_SZ + hbase;

  f32x4 av[4], sv[4], bi[4], br[4];
#pragma unroll
  for (int q = 0; q < 4; ++q) {
    av[q] = *reinterpret_cast<const f32x4*>(&ldsC[bl][c * 16 + q * 4]);
    sv[q] = *reinterpret_cast<const f32x4*>(&state[e + q * 4]);
    bi[q] = *reinterpret_cast<const f32x4*>(&b_in[hbase + q * 4]);
    br[q] = *reinterpret_cast<const f32x4*>(&b_rec[hbase + q * 4]);
  }

  f16x8 vh0, vm0, vh1, vm1;
#pragma unroll
  for (int q = 0; q < 4; ++q) {
    f32x4 so, oo;
#pragma unroll
    for (int j = 0; j < 4; ++j) {
      const int idx = q * 4 + j;
      const int h = hbase + idx;
      const float sig = (h < 1024 || h >= 1536) ? 0.1f : 0.0f;
      const float n = jax_normal(kk0, kk1, (unsigned)(e + idx));
      float s = sv[q][j] * 0.6666666865348816f +
                (av[q][j] + bi[q][j] + br[q][j]) * 0.3333333432674408f;
      s += sig * n;
      const float o = fmaxf(s, 0.0f);
      so[j] = s; oo[j] = o;
      _Float16 xh, xm;
      split2(o, xh, xm);
      if (idx < 8) { vh0[idx] = xh; vm0[idx] = xm; }
      else         { vh1[idx - 8] = xh; vm1[idx - 8] = xm; }
    }
    *reinterpret_cast<f32x4*>(&state[e + q * 4]) = so;
    *reinterpret_cast<f32x4*>(&out_t[e + q * 4]) = oo;
  }

  // pack next-step A fragments (fp16 2-way)
  const int bf = b >> 4;
  const int sA = hb * 2 + (c >> 1);
  _Float16* dstbase = Apk_next + ((size_t)(bf * NSTEP_REC + sA) * 2) * 512;
  const int oct0 = (c * 2) & 3;
  const int off0 = ((b & 15) + 16 * oct0) * 8;
  const int off1 = ((b & 15) + 16 * (oct0 + 1)) * 8;
  *reinterpret_cast<f16x8*>(dstbase + off0)       = vh0;
  *reinterpret_cast<f16x8*>(dstbase + 512 + off0) = vm0;
  *reinterpret_cast<f16x8*>(dstbase + off1)       = vh1;
  *reinterpret_cast<f16x8*>(dstbase + 512 + off1) = vm1;
}

__global__ void finalize_kernel(const float* __restrict__ state,
                                const float* __restrict__ last_out,
                                float* __restrict__ dst) {
  const int i = blockIdx.x * 256 + threadIdx.x;
  dst[i] = state[i];
  dst[BH + i] = last_out[i];
}

extern "C" void kernel_launch(void* const* d_in, const int* in_sizes, int n_in,
                              void* d_out, int out_size, void* d_ws, size_t ws_size,
                              hipStream_t stream) {
  const float* inputs = (const float*)d_in[0];
  const float* W_in   = (const float*)d_in[1];
  const float* b_in   = (const float*)d_in[2];
  const float* W_rec  = (const float*)d_in[3];
  const float* b_rec  = (const float*)d_in[4];
  float* out = (float*)d_out;

  char* ws = (char*)d_ws;
  _Float16* Bpk = (_Float16*)ws;                        // 13,991,936 B
  _Float16* Xpk = (_Float16*)(ws + 13991936);           // 41,943,040 B
  _Float16* Apk = (_Float16*)(ws + 55934976);           // 3,670,016 B
  float* state  = (float*)(ws + 59604992);              // 1,835,008 B
  unsigned* keybuf = (unsigned*)(ws + 61440000);        // 2,048 B

  init_keys_kernel<<<1, 256, 0, stream>>>(keybuf);
  pack_B_kernel<<<1708, 256, 0, stream>>>(W_in, W_rec, Bpk);
  pack_x_kernel<<<5120, 256, 0, stream>>>(inputs, Xpk);
  zero_kernel<<<1792, 256, 0, stream>>>(state, BH);
  zero_kernel<<<1792, 256, 0, stream>>>((float*)Apk, APK_HALF / 2);

  for (int t = 0; t < T_STEPS; ++t) {
    const int par = t & 1;
    eirnn_step<<<112, 256, 0, stream>>>(
        Apk + (size_t)par * APK_HALF,
        Apk + (size_t)(par ^ 1) * APK_HALF,
        Xpk + (size_t)t * (16 * NSTEP_X * 2 * 512),
        Bpk, state, b_in, b_rec, keybuf, out + (size_t)t * BH, t);
  }

  finalize_kernel<<<1792, 256, 0, stream>>>(
      state, out + (size_t)(T_STEPS - 1) * BH, out + (size_t)T_STEPS * BH);
}

// Round 6
// 3653.798 us; speedup vs baseline: 9.6243x; 2.3540x over previous
//
#include <hip/hip_runtime.h>

#define T_STEPS 256
#define B_SZ 256
#define H_SZ 1792
#define IN_SZ 160
#define BH (B_SZ * H_SZ) /* 458752 */
#define NSTEP_REC 56
#define NSTEP_X 5
#define NFRAG_H 112
#define APK_HALF (16 * NSTEP_REC * 2 * 512) /* fp16 elems per A buffer */

typedef __attribute__((ext_vector_type(8))) _Float16 f16x8;
typedef __attribute__((ext_vector_type(4))) _Float16 f16x4;
typedef __attribute__((ext_vector_type(4))) float f32x4;

__device__ __forceinline__ unsigned rotl32(unsigned x, int r) {
  return (x << r) | (x >> (32 - r));
}

__device__ __forceinline__ void threefry2x32(unsigned k0, unsigned k1,
                                             unsigned x0, unsigned x1,
                                             unsigned& o0, unsigned& o1) {
  unsigned ks2 = k0 ^ k1 ^ 0x1BD11BDAu;
  x0 += k0; x1 += k1;
#define TF_R(r) { x0 += x1; x1 = rotl32(x1, (r)); x1 ^= x0; }
  TF_R(13) TF_R(15) TF_R(26) TF_R(6)
  x0 += k1; x1 += ks2 + 1u;
  TF_R(17) TF_R(29) TF_R(16) TF_R(24)
  x0 += ks2; x1 += k0 + 2u;
  TF_R(13) TF_R(15) TF_R(26) TF_R(6)
  x0 += k0; x1 += k1 + 3u;
  TF_R(17) TF_R(29) TF_R(16) TF_R(24)
  x0 += k1; x1 += ks2 + 4u;
  TF_R(13) TF_R(15) TF_R(26) TF_R(6)
  x0 += ks2; x1 += k0 + 5u;
#undef TF_R
  o0 = x0; o1 = x1;
}

__device__ __forceinline__ float erfinv_f32(float x) {
  float w = -log1pf(-x * x);
  float p;
  if (w < 5.0f) {
    w -= 2.5f;
    p = 2.81022636e-08f;
    p = fmaf(p, w, 3.43273939e-07f);
    p = fmaf(p, w, -3.5233877e-06f);
    p = fmaf(p, w, -4.39150654e-06f);
    p = fmaf(p, w, 0.00021858087f);
    p = fmaf(p, w, -0.00125372503f);
    p = fmaf(p, w, -0.00417768164f);
    p = fmaf(p, w, 0.246640727f);
    p = fmaf(p, w, 1.50140941f);
  } else {
    w = sqrtf(w) - 3.0f;
    p = -0.000200214257f;
    p = fmaf(p, w, 0.000100950558f);
    p = fmaf(p, w, 0.00134934322f);
    p = fmaf(p, w, -0.00367342844f);
    p = fmaf(p, w, 0.00573950773f);
    p = fmaf(p, w, -0.0076224613f);
    p = fmaf(p, w, 0.00943887047f);
    p = fmaf(p, w, 1.00167406f);
    p = fmaf(p, w, 2.83297682f);
  }
  return p * x;
}

// JAX partitionable threefry bits = o0 ^ o1 of threefry(key, (0, e)).
__device__ __forceinline__ float jax_normal(unsigned k0, unsigned k1, unsigned e) {
  unsigned o0, o1;
  threefry2x32(k0, k1, 0u, e, o0, o1);
  const unsigned bits = o0 ^ o1;
  float u = __uint_as_float((bits >> 9) | 0x3F800000u) - 1.0f;
  float z = u * 2.0f + (-0.99999994f);
  z = fmaxf(-0.99999994f, z);
  return 1.4142135623730951f * erfinv_f32(z);
}

__global__ void init_keys_kernel(unsigned* __restrict__ keybuf) {
  const unsigned t = threadIdx.x;
  unsigned o0, o1;
  threefry2x32(0u, 42u, 0u, t, o0, o1);
  keybuf[2 * t] = o0;
  keybuf[2 * t + 1] = o1;
}

// fp16 2-way split: w ~= h + m/2048 (m pre-scaled to stay normal).
__device__ __forceinline__ void split2(float w, _Float16& h, _Float16& m) {
  h = (_Float16)w;
  float r = w - (float)h;
  m = (_Float16)(r * 2048.0f);
}

// B_pk[s][f][p][512] : frag elem(lane,j) = B[k=32s+8*(lane>>4)+j][h=16f+(lane&15)]
__global__ void pack_B_kernel(const float* __restrict__ W_in,
                              const float* __restrict__ W_rec,
                              _Float16* __restrict__ Bpk) {
  const int id = blockIdx.x * 256 + threadIdx.x; // 437248
  const int h = id / 244;
  const int ko = id - h * 244;
  const int k0 = ko * 8;
  float w[8];
  if (k0 < H_SZ) {
    const float4* src = reinterpret_cast<const float4*>(&W_rec[(size_t)h * H_SZ + k0]);
    float4 v0 = src[0], v1 = src[1];
    float m;
    if (h < 512)       m = (k0 < 1536) ? 1.0f : 0.0f;
    else if (h < 1536) m = 1.0f;
    else               m = (k0 >= 512) ? 1.0f : 0.0f;
    w[0]=v0.x*m; w[1]=v0.y*m; w[2]=v0.z*m; w[3]=v0.w*m;
    w[4]=v1.x*m; w[5]=v1.y*m; w[6]=v1.z*m; w[7]=v1.w*m;
  } else {
    const int i0 = k0 - H_SZ;
    const float4* src = reinterpret_cast<const float4*>(&W_in[(size_t)h * IN_SZ + i0]);
    float4 v0 = src[0], v1 = src[1];
    float m;
    if (h < 512)       m = (i0 < 128) ? 1.0f : 0.0f;
    else if (h < 1536) m = (i0 >= 128) ? 1.0f : 0.0f;
    else               m = (i0 >= 64 && i0 < 128) ? 1.0f : 0.0f;
    w[0]=v0.x*m; w[1]=v0.y*m; w[2]=v0.z*m; w[3]=v0.w*m;
    w[4]=v1.x*m; w[5]=v1.y*m; w[6]=v1.z*m; w[7]=v1.w*m;
  }
  f16x8 vh, vm;
#pragma unroll
  for (int j = 0; j < 8; ++j) {
    _Float16 a, b;
    split2(w[j], a, b);
    vh[j] = a; vm[j] = b;
  }
  const int s = ko >> 2;
  const int f = h >> 4;
  const int lane = (h & 15) + 16 * (ko & 3);
  _Float16* dst = Bpk + ((size_t)(s * NFRAG_H + f) * 2) * 512 + lane * 8;
  *reinterpret_cast<f16x8*>(dst)       = vh;
  *reinterpret_cast<f16x8*>(dst + 512) = vm;
}

// X_pk[t][bf][sx][p][512] : elem(lane,j) = x[t][b=16bf+(lane&15)][i=32sx+8*(lane>>4)+j]
__global__ void pack_x_kernel(const float* __restrict__ inputs,
                              _Float16* __restrict__ Xpk) {
  const int id = blockIdx.x * 256 + threadIdx.x; // 1310720
  const int io = id % 20;
  const int tb = id / 20;
  const int b = tb & 255;
  const int t = tb >> 8;
  const float4* src = reinterpret_cast<const float4*>(
      &inputs[((size_t)(t * 256 + b)) * IN_SZ + io * 8]);
  float4 v0 = src[0], v1 = src[1];
  float w[8] = {v0.x, v0.y, v0.z, v0.w, v1.x, v1.y, v1.z, v1.w};
  f16x8 vh, vm;
#pragma unroll
  for (int j = 0; j < 8; ++j) {
    _Float16 a, bb;
    split2(w[j], a, bb);
    vh[j] = a; vm[j] = bb;
  }
  const int sx = io >> 2;
  const int lane = (b & 15) + 16 * (io & 3);
  _Float16* dst = Xpk +
      ((size_t)((t * 16 + (b >> 4)) * NSTEP_X + sx) * 2) * 512 + lane * 8;
  *reinterpret_cast<f16x8*>(dst)       = vh;
  *reinterpret_cast<f16x8*>(dst + 512) = vm;
}

__global__ void zero_kernel(float* __restrict__ p, int n) {
  const int i = blockIdx.x * 256 + threadIdx.x;
  if (i < n) p[i] = 0.0f;
}

// grid 224 = 8 bb (32b) x 28 hb (64h); 512 thr = 8 waves, intra-block split-k:
// wave w handles k-steps s = w, w+8, ... (7-8 steps), full 2x4 frag tile each.
__global__ __launch_bounds__(512, 2) void eirnn_step(
    const _Float16* __restrict__ Apk_cur,
    _Float16* __restrict__ Apk_next,
    const _Float16* __restrict__ Xpk_t,
    const _Float16* __restrict__ Bpk,
    float* __restrict__ state,
    const float* __restrict__ b_in, const float* __restrict__ b_rec,
    const unsigned* __restrict__ keybuf,
    float* __restrict__ out_t, int t) {
  __shared__ float ldsC[8][32][68];

  const int tid = threadIdx.x;
  const int w = tid >> 6;
  const int lane = tid & 63;
  // XCD-chunked swizzle: XCD x owns contiguous logical range -> ~4 hb values.
  const int logical = (blockIdx.x & 7) * 28 + (blockIdx.x >> 3);
  const int hb = logical >> 3; // 0..27
  const int bb = logical & 7;  // 0..7
  const int b0 = bb * 32;

  // ---- epilogue geometry + noise precompute (independent of GEMM; VALU
  // overlaps other waves' k-loop memory waits) ----
  const int bl = tid >> 4; // 0..31
  const int q  = tid & 15; // 0..15
  const int h0 = hb * 64 + q * 4;
  const size_t e0 = (size_t)(b0 + bl) * H_SZ + h0;
  const float sig = (h0 < 1024 || h0 >= 1536) ? 0.1f : 0.0f;
  float nz[4] = {0.0f, 0.0f, 0.0f, 0.0f};
  if (sig != 0.0f) {
    const unsigned kk0 = keybuf[2 * t], kk1 = keybuf[2 * t + 1];
#pragma unroll
    for (int j = 0; j < 4; ++j)
      nz[j] = jax_normal(kk0, kk1, (unsigned)(e0 + j));
  }

  // ---- GEMM: wave-disjoint k-slices, register double-buffer ----
  const int bf0 = b0 >> 4; // 2 A-frags
  const int f0 = hb * 4;   // 4 B-frags
  const int lofs = lane * 8;

  f32x4 acc1[2][4] = {};
  f32x4 acc2[2][4] = {};
  f16x8 bufA[2][2][2]; // [par][pi][plane]
  f16x8 bufB[2][4][2]; // [par][qi][plane]

#define LOAD_REC(PAR, S)                                                        \
  { const int s_ = (S);                                                         \
    _Pragma("unroll")                                                           \
    for (int pi = 0; pi < 2; ++pi) {                                            \
      const _Float16* ap =                                                      \
          Apk_cur + ((size_t)((bf0 + pi) * NSTEP_REC + s_) * 2) * 512 + lofs;   \
      bufA[PAR][pi][0] = *reinterpret_cast<const f16x8*>(ap);                   \
      bufA[PAR][pi][1] = *reinterpret_cast<const f16x8*>(ap + 512);             \
    }                                                                           \
    _Pragma("unroll")                                                           \
    for (int qi = 0; qi < 4; ++qi) {                                            \
      const _Float16* bp =                                                      \
          Bpk + ((size_t)(s_ * NFRAG_H + f0 + qi) * 2) * 512 + lofs;            \
      bufB[PAR][qi][0] = *reinterpret_cast<const f16x8*>(bp);                   \
      bufB[PAR][qi][1] = *reinterpret_cast<const f16x8*>(bp + 512);             \
    } }

#define LOAD_X(PAR, SX)                                                         \
  { const int sx_ = (SX);                                                       \
    _Pragma("unroll")                                                           \
    for (int pi = 0; pi < 2; ++pi) {                                            \
      const _Float16* ap =                                                      \
          Xpk_t + ((size_t)((bf0 + pi) * NSTEP_X + sx_) * 2) * 512 + lofs;      \
      bufA[PAR][pi][0] = *reinterpret_cast<const f16x8*>(ap);                   \
      bufA[PAR][pi][1] = *reinterpret_cast<const f16x8*>(ap + 512);             \
    }                                                                           \
    _Pragma("unroll")                                                           \
    for (int qi = 0; qi < 4; ++qi) {                                            \
      const _Float16* bp =                                                      \
          Bpk + ((size_t)((NSTEP_REC + sx_) * NFRAG_H + f0 + qi) * 2) * 512 + lofs; \
      bufB[PAR][qi][0] = *reinterpret_cast<const f16x8*>(bp);                   \
      bufB[PAR][qi][1] = *reinterpret_cast<const f16x8*>(bp + 512);             \
    } }

#define MFMA_STEP(PAR)                                                          \
  { _Pragma("unroll")                                                           \
    for (int pi = 0; pi < 2; ++pi)                                              \
      _Pragma("unroll")                                                         \
      for (int qi = 0; qi < 4; ++qi) {                                          \
        acc1[pi][qi] = __builtin_amdgcn_mfma_f32_16x16x32_f16(                  \
            bufA[PAR][pi][0], bufB[PAR][qi][0], acc1[pi][qi], 0, 0, 0);         \
        acc2[pi][qi] = __builtin_amdgcn_mfma_f32_16x16x32_f16(                  \
            bufA[PAR][pi][0], bufB[PAR][qi][1], acc2[pi][qi], 0, 0, 0);         \
        acc2[pi][qi] = __builtin_amdgcn_mfma_f32_16x16x32_f16(                  \
            bufA[PAR][pi][1], bufB[PAR][qi][0], acc2[pi][qi], 0, 0, 0);         \
      } }

  LOAD_REC(0, w)
#pragma unroll
  for (int i = 1; i < 7; ++i) {
    if (i & 1) { LOAD_REC(1, w + 8 * i) MFMA_STEP(0) }
    else       { LOAD_REC(0, w + 8 * i) MFMA_STEP(1) }
  }
  // pending: par0 holds s = w+48
  if (w < 5) { // waves 0..4 take the 5 input k-steps (global s = 56+w)
    LOAD_X(1, w)
    MFMA_STEP(0)
    MFMA_STEP(1)
  } else {
    MFMA_STEP(0)
  }
#undef LOAD_REC
#undef LOAD_X
#undef MFMA_STEP

  // scatter partials: row = b-local, col = h-local (validated R4/R5 mapping)
#pragma unroll
  for (int pi = 0; pi < 2; ++pi)
#pragma unroll
    for (int qi = 0; qi < 4; ++qi) {
      const int row = pi * 16 + ((lane >> 4) << 2);
      const int col = qi * 16 + (lane & 15);
#pragma unroll
      for (int r = 0; r < 4; ++r)
        ldsC[w][row + r][col] =
            acc1[pi][qi][r] + acc2[pi][qi][r] * (1.0f / 2048.0f);
    }
  __syncthreads();

  // ---- reduce 8 partials + state update + pack next A ----
  f32x4 sum = {0.0f, 0.0f, 0.0f, 0.0f};
#pragma unroll
  for (int ww = 0; ww < 8; ++ww)
    sum += *reinterpret_cast<const f32x4*>(&ldsC[ww][bl][q * 4]);

  const f32x4 sv = *reinterpret_cast<const f32x4*>(&state[e0]);
  const f32x4 bi = *reinterpret_cast<const f32x4*>(&b_in[h0]);
  const f32x4 br = *reinterpret_cast<const f32x4*>(&b_rec[h0]);
  f32x4 so, oo;
  f16x4 vh, vm;
#pragma unroll
  for (int j = 0; j < 4; ++j) {
    float s = sv[j] * 0.6666666865348816f +
              (sum[j] + bi[j] + br[j]) * 0.3333333432674408f;
    s += sig * nz[j];
    const float o = fmaxf(s, 0.0f);
    so[j] = s; oo[j] = o;
    _Float16 xh, xm;
    split2(o, xh, xm);
    vh[j] = xh; vm[j] = xm;
  }
  *reinterpret_cast<f32x4*>(&state[e0]) = so;
  *reinterpret_cast<f32x4*>(&out_t[e0]) = oo;

  const int b = b0 + bl;
  _Float16* dst = Apk_next +
      ((size_t)((b >> 4) * NSTEP_REC + hb * 2 + (q >> 3)) * 2) * 512 +
      ((b & 15) + 16 * ((q >> 1) & 3)) * 8 + (q & 1) * 4;
  *reinterpret_cast<f16x4*>(dst)       = vh;
  *reinterpret_cast<f16x4*>(dst + 512) = vm;
}

__global__ void finalize_kernel(const float* __restrict__ state,
                                const float* __restrict__ last_out,
                                float* __restrict__ dst) {
  const int i = blockIdx.x * 256 + threadIdx.x;
  dst[i] = state[i];
  dst[BH + i] = last_out[i];
}

extern "C" void kernel_launch(void* const* d_in, const int* in_sizes, int n_in,
                              void* d_out, int out_size, void* d_ws, size_t ws_size,
                              hipStream_t stream) {
  const float* inputs = (const float*)d_in[0];
  const float* W_in   = (const float*)d_in[1];
  const float* b_in   = (const float*)d_in[2];
  const float* W_rec  = (const float*)d_in[3];
  const float* b_rec  = (const float*)d_in[4];
  float* out = (float*)d_out;

  char* ws = (char*)d_ws;
  _Float16* Bpk = (_Float16*)ws;                 // 13,991,936 B
  _Float16* Xpk = (_Float16*)(ws + 13991936);    // 41,943,040 B
  _Float16* Apk = (_Float16*)(ws + 55934976);    // 3,670,016 B
  float* state  = (float*)(ws + 59604992);       // 1,835,008 B
  unsigned* keybuf = (unsigned*)(ws + 61440000); // 2,048 B

  init_keys_kernel<<<1, 256, 0, stream>>>(keybuf);
  pack_B_kernel<<<1708, 256, 0, stream>>>(W_in, W_rec, Bpk);
  pack_x_kernel<<<5120, 256, 0, stream>>>(inputs, Xpk);
  zero_kernel<<<1792, 256, 0, stream>>>(state, BH);
  zero_kernel<<<1792, 256, 0, stream>>>((float*)Apk, APK_HALF / 2);

  for (int t = 0; t < T_STEPS; ++t) {
    const int par = t & 1;
    eirnn_step<<<224, 512, 0, stream>>>(
        Apk + (size_t)par * APK_HALF,
        Apk + (size_t)(par ^ 1) * APK_HALF,
        Xpk + (size_t)t * (16 * NSTEP_X * 2 * 512),
        Bpk, state, b_in, b_rec, keybuf, out + (size_t)t * BH, t);
  }

  finalize_kernel<<<1792, 256, 0, stream>>>(
      state, out + (size_t)(T_STEPS - 1) * BH, out + (size_t)T_STEPS * BH);
}